// Round 12
// baseline (867.097 us; speedup 1.0000x reference)
//
#include <hip/hip_runtime.h>

#define SEQ   2048
#define BATCH 2
#define DMODEL 1024
#define DFF   4096
#define NHEAD 16
#define HDIM  64
#define NTOK  (BATCH*SEQ)   // 4096

typedef short s8v __attribute__((ext_vector_type(8)));
typedef float f4v __attribute__((ext_vector_type(4)));

__device__ __forceinline__ float b2f(unsigned short u) {
    union { unsigned int i; float f; } v; v.i = ((unsigned int)u) << 16; return v.f;
}
__device__ __forceinline__ unsigned short f2b(float f) {
    union { unsigned int i; float f; } v; v.f = f;
    unsigned int r = v.i + 0x7FFFu + ((v.i >> 16) & 1u);
    return (unsigned short)(r >> 16);
}

__device__ __forceinline__ f4v mfma_bf16(s8v a, s8v b, f4v c) {
    return __builtin_amdgcn_mfma_f32_16x16x32_bf16(a, b, c, 0, 0, 0);
}

__device__ __forceinline__ void gload_lds16(const void* g, void* l) {
    __builtin_amdgcn_global_load_lds(
        (const __attribute__((address_space(1))) unsigned int*)g,
        (__attribute__((address_space(3))) unsigned int*)l, 16, 0, 0);
}

// ---------------- one tile of fp32->bf16 transpose ----------------
__device__ __forceinline__ void tp_tile(const float* __restrict__ src,
                                        unsigned short* __restrict__ dst,
                                        int R, int C, int br, int bc, int t,
                                        unsigned short* tl) {
    for (int i = 0; i < 16; i++) {
        int idx = t + 256 * i;
        int r = idx >> 6, c = idx & 63;
        tl[r * 65 + c] = f2b(src[(size_t)(br * 64 + r) * C + bc * 64 + c]);
    }
    __syncthreads();
    for (int i = 0; i < 16; i++) {
        int idx = t + 256 * i;
        int r2 = idx >> 6, c2 = idx & 63;
        dst[(size_t)(bc * 64 + r2) * R + br * 64 + c2] = tl[c2 * 65 + r2];
    }
}

// ---------------- fused prep: all 6 weight transposes + bias concat, one launch --------
// grid (16,16,6): z<4 -> 1024x1024 mats; z=4 -> W1 (4 tiles/block); z=5 -> W2 (+ concat)
__global__ __launch_bounds__(256) void prep_weights(const float* __restrict__ Wq,
                                                    const float* __restrict__ Wk,
                                                    const float* __restrict__ Wv,
                                                    const float* __restrict__ Wo,
                                                    const float* __restrict__ W1,
                                                    const float* __restrict__ W2,
                                                    const float* __restrict__ bq,
                                                    const float* __restrict__ bk,
                                                    const float* __restrict__ bv,
                                                    unsigned short* __restrict__ Wqkv_t,
                                                    unsigned short* __restrict__ Wo_t,
                                                    unsigned short* __restrict__ W1_t,
                                                    unsigned short* __restrict__ W2_t,
                                                    float* __restrict__ bqkv) {
    __shared__ unsigned short tl[64 * 65];
    const int t = threadIdx.x;
    const int bx = blockIdx.x, by = blockIdx.y, z = blockIdx.z;
    if (z < 4) {
        const float* src = (z == 0) ? Wq : (z == 1) ? Wk : (z == 2) ? Wv : Wo;
        unsigned short* dst = (z == 3) ? Wo_t : Wqkv_t + (size_t)z * 1024 * 1024;
        tp_tile(src, dst, 1024, 1024, bx, by, t, tl);
    } else if (z == 4) {
        for (int i = 0; i < 4; i++) {
            tp_tile(W1, W1_t, 1024, 4096, bx, by + 16 * i, t, tl);
            __syncthreads();
        }
    } else {
        if (bx == 0 && by == 0) {
            for (int i = 0; i < 12; i++) {
                int idx = t + 256 * i;
                if (idx < 1024) bqkv[idx] = bq[idx];
                else if (idx < 2048) bqkv[idx] = bk[idx - 1024];
                else if (idx < 3072) bqkv[idx] = bv[idx - 2048];
            }
        }
        for (int i = 0; i < 4; i++) {
            tp_tile(W2, W2_t, 4096, 1024, bx + 16 * i, by, t, tl);
            __syncthreads();
        }
    }
}

// ---------------- pack V only: Vb [key][d] -> Vc swizzled [d][key] tiles ----------------
__global__ __launch_bounds__(256) void pack_v(const unsigned short* __restrict__ Vb,
                                              unsigned short* __restrict__ Vc) {
    __shared__ unsigned short tl[64 * 65];
    const int t = threadIdx.x;
    const int kt = blockIdx.x, h = blockIdx.y, b = blockIdx.z;
    const unsigned short* srcV = Vb + (size_t)b * SEQ * 1024 + h * HDIM;
    for (int i = 0; i < 16; i++) {
        int idx = t + 256 * i;
        int r = idx >> 6, c = idx & 63;      // r = key local, c = d
        tl[r * 65 + c] = srcV[(size_t)(kt * 64 + r) * 1024 + c];
    }
    __syncthreads();
    unsigned short* dstV = Vc + ((size_t)((b * NHEAD + h) * 32 + kt)) * 4096;
    for (int i = 0; i < 2; i++) {
        int ci = t + 256 * i;
        int r = ci >> 3, cp = ci & 7;        // r = d
        int cl = cp ^ (r & 7);
        ushort4 e0, e1;
        e0.x = tl[(cl * 8 + 0) * 65 + r]; e0.y = tl[(cl * 8 + 1) * 65 + r];
        e0.z = tl[(cl * 8 + 2) * 65 + r]; e0.w = tl[(cl * 8 + 3) * 65 + r];
        e1.x = tl[(cl * 8 + 4) * 65 + r]; e1.y = tl[(cl * 8 + 5) * 65 + r];
        e1.z = tl[(cl * 8 + 6) * 65 + r]; e1.w = tl[(cl * 8 + 7) * 65 + r];
        *(ushort4*)&dstV[ci * 8]     = e0;
        *(ushort4*)&dstV[ci * 8 + 4] = e1;
    }
}

// ---------------- layernorm fp32 in -> bf16 out (torch: ddof=1, eps on std) ----------------
__global__ __launch_bounds__(256) void ln_kernel(const float* __restrict__ x,
                                                 const float* __restrict__ al,
                                                 const float* __restrict__ be,
                                                 unsigned short* __restrict__ o) {
    const int row = blockIdx.x;
    const float* xr = x + (size_t)row * DMODEL;
    float4 u = ((const float4*)xr)[threadIdx.x];
    float v[4] = { u.x, u.y, u.z, u.w };
    float s = v[0] + v[1] + v[2] + v[3];
    float sq = v[0]*v[0] + v[1]*v[1] + v[2]*v[2] + v[3]*v[3];
    for (int off = 32; off; off >>= 1) { s += __shfl_xor(s, off); sq += __shfl_xor(sq, off); }
    __shared__ float red[8];
    int wave = threadIdx.x >> 6, lane = threadIdx.x & 63;
    if (!lane) { red[wave] = s; red[4 + wave] = sq; }
    __syncthreads();
    s = red[0] + red[1] + red[2] + red[3];
    sq = red[4] + red[5] + red[6] + red[7];
    float mean = s * (1.f / DMODEL);
    float var = (sq - (float)DMODEL * mean * mean) * (1.f / (DMODEL - 1));
    var = var < 0.f ? 0.f : var;
    float inv = al[0] / (sqrtf(var) + 1e-6f);
    float bt = be[0];
    uint2 ou;
    unsigned short r0 = f2b((v[0] - mean) * inv + bt);
    unsigned short r1 = f2b((v[1] - mean) * inv + bt);
    unsigned short r2 = f2b((v[2] - mean) * inv + bt);
    unsigned short r3 = f2b((v[3] - mean) * inv + bt);
    ou.x = (unsigned int)r0 | ((unsigned int)r1 << 16);
    ou.y = (unsigned int)r2 | ((unsigned int)r3 << 16);
    ((uint2*)(o + (size_t)row * DMODEL))[threadIdx.x] = ou;
}

// ---------------- m97-style GEMM (128x128): C = [relu](A @ Bt^T + bias) [+ res] ----------
// SPLIT3: Q (cols<1024, pre-scaled x0.125) -> C block 0; K (1024..2048) -> Kc packed
// swizzled tiles; V (>=2048) -> C block 2. Q-scale is bit-exact (power-of-2).
template<bool RELU, bool RES, typename CT, bool SPLIT3 = false>
__global__ __launch_bounds__(256) void gemm_bt(const unsigned short* __restrict__ A,
                                               const unsigned short* __restrict__ Bt,
                                               const float* __restrict__ bias,
                                               const float* __restrict__ res,
                                               CT* __restrict__ C,
                                               unsigned short* __restrict__ Kc,
                                               int M, int N, int K) {
    __shared__ __align__(16) unsigned short smA[128 * 32];
    __shared__ __align__(16) unsigned short smB[128 * 32];
    const int t = threadIdx.x;
    const int wave = t >> 6, lane = t & 63;
    const int quad = lane >> 4, l16 = lane & 15;
    const int wm = wave & 1, wn = wave >> 1;
    const int m0 = blockIdx.x * 128, n0 = blockIdx.y * 128;

    f4v acc[4][4] = {};

    const int c0 = t, c1 = t + 256;
    const int rA0 = c0 >> 2, sA0 = c0 & 3;
    const int rA1 = c1 >> 2, sA1 = c1 & 3;

    for (int k0 = 0; k0 < K; k0 += 32) {
        __syncthreads();
        gload_lds16(A  + (size_t)(m0 + rA0) * K + k0 + sA0 * 8, smA + c0 * 8);
        gload_lds16(A  + (size_t)(m0 + rA1) * K + k0 + sA1 * 8, smA + c1 * 8);
        gload_lds16(Bt + (size_t)(n0 + rA0) * K + k0 + sA0 * 8, smB + c0 * 8);
        gload_lds16(Bt + (size_t)(n0 + rA1) * K + k0 + sA1 * 8, smB + c1 * 8);
        __syncthreads();
        s8v a[4], b[4];
        for (int i = 0; i < 4; i++)
            a[i] = *(const s8v*)&smA[(wm * 64 + i * 16 + l16) * 32 + quad * 8];
        for (int i = 0; i < 4; i++)
            b[i] = *(const s8v*)&smB[(wn * 64 + i * 16 + l16) * 32 + quad * 8];
        for (int mi = 0; mi < 4; mi++)
            for (int ni = 0; ni < 4; ni++)
                acc[mi][ni] = mfma_bf16(a[mi], b[ni], acc[mi][ni]);
    }

    for (int mi = 0; mi < 4; mi++) {
        for (int ni = 0; ni < 4; ni++) {
            int col = n0 + wn * 64 + ni * 16 + l16;
            float bv = bias[col];
            for (int r = 0; r < 4; r++) {
                int row = m0 + wm * 64 + mi * 16 + quad * 4 + r;
                float v = acc[mi][ni][r] + bv;
                if (RELU) v = v > 0.f ? v : 0.f;
                if (RES) v += res[(size_t)row * N + col];
                if constexpr (SPLIT3) {
                    if (col < 1024) {
                        C[(size_t)row * 1024 + col] = f2b(v * 0.125f);
                    } else if (col < 2048) {
                        int d = col - 1024;
                        int h = d >> 6, dl = d & 63;
                        int bb = row >> 11, sl = row & 2047;
                        int kt = sl >> 6, rl = sl & 63;
                        Kc[((size_t)((bb * NHEAD + h) * 32 + kt)) * 4096
                           + rl * 64 + (((dl >> 3) ^ (rl & 7)) * 8) + (dl & 7)] = f2b(v);
                    } else {
                        C[2 * (size_t)NTOK * 1024 + (size_t)row * 1024 + (col - 2048)] = f2b(v);
                    }
                } else {
                    size_t cidx = (size_t)row * N + col;
                    if constexpr (sizeof(CT) == 2)
                        C[cidx] = f2b(v);
                    else
                        C[cidx] = v;
                }
            }
        }
    }
}

// ---------------- ff2 split-K=2 (M=4096, N=1024, K=4096, 128x128 tile) ----------------
__global__ __launch_bounds__(256) void ff2_splitk(const unsigned short* __restrict__ A,
                                                  const unsigned short* __restrict__ Bt,
                                                  const float* __restrict__ bias,
                                                  const float* __restrict__ res,
                                                  float* __restrict__ out,
                                                  float* __restrict__ pbuf) {
    const int K = 4096, N = 1024;
    __shared__ __align__(16) unsigned short smA[128 * 32];
    __shared__ __align__(16) unsigned short smB[128 * 32];
    const int t = threadIdx.x;
    const int wave = t >> 6, lane = t & 63;
    const int quad = lane >> 4, l16 = lane & 15;
    const int wm = wave & 1, wn = wave >> 1;
    const int m0 = blockIdx.x * 128, n0 = blockIdx.y * 128;
    const int z = blockIdx.z;
    const int kbeg = z * 2048, kend = kbeg + 2048;

    f4v acc[4][4] = {};

    const int c0 = t, c1 = t + 256;
    const int rA0 = c0 >> 2, sA0 = c0 & 3;
    const int rA1 = c1 >> 2, sA1 = c1 & 3;

    for (int k0 = kbeg; k0 < kend; k0 += 32) {
        __syncthreads();
        gload_lds16(A  + (size_t)(m0 + rA0) * K + k0 + sA0 * 8, smA + c0 * 8);
        gload_lds16(A  + (size_t)(m0 + rA1) * K + k0 + sA1 * 8, smA + c1 * 8);
        gload_lds16(Bt + (size_t)(n0 + rA0) * K + k0 + sA0 * 8, smB + c0 * 8);
        gload_lds16(Bt + (size_t)(n0 + rA1) * K + k0 + sA1 * 8, smB + c1 * 8);
        __syncthreads();
        s8v a[4], b[4];
        for (int i = 0; i < 4; i++)
            a[i] = *(const s8v*)&smA[(wm * 64 + i * 16 + l16) * 32 + quad * 8];
        for (int i = 0; i < 4; i++)
            b[i] = *(const s8v*)&smB[(wn * 64 + i * 16 + l16) * 32 + quad * 8];
        for (int mi = 0; mi < 4; mi++)
            for (int ni = 0; ni < 4; ni++)
                acc[mi][ni] = mfma_bf16(a[mi], b[ni], acc[mi][ni]);
    }

    for (int mi = 0; mi < 4; mi++) {
        for (int ni = 0; ni < 4; ni++) {
            int col = n0 + wn * 64 + ni * 16 + l16;
            for (int r = 0; r < 4; r++) {
                int row = m0 + wm * 64 + mi * 16 + quad * 4 + r;
                size_t idx = (size_t)row * N + col;
                if (z == 0)
                    out[idx] = acc[mi][ni][r] + bias[col] + res[idx];
                else
                    pbuf[idx] = acc[mi][ni][r];
            }
        }
    }
}

// ---------------- combine: out += Pbuf ----------------
__global__ __launch_bounds__(256) void add_pbuf(float* __restrict__ out,
                                                const float* __restrict__ pbuf) {
    const int i0 = (blockIdx.x * 256 + threadIdx.x) * 8;
    float4 a0 = *(const float4*)&out[i0];
    float4 a1 = *(const float4*)&out[i0 + 4];
    float4 p0 = *(const float4*)&pbuf[i0];
    float4 p1 = *(const float4*)&pbuf[i0 + 4];
    a0.x += p0.x; a0.y += p0.y; a0.z += p0.z; a0.w += p0.w;
    a1.x += p1.x; a1.y += p1.y; a1.z += p1.z; a1.w += p1.w;
    *(float4*)&out[i0]     = a0;
    *(float4*)&out[i0 + 4] = a1;
}

// ---------------- flash attention: 64 q/block, fixed-max softmax (Q pre-scaled) ---------
__global__ __launch_bounds__(256) void attn_kernel(const unsigned short* __restrict__ Qb,
                                                   const unsigned short* __restrict__ Kc,
                                                   const unsigned short* __restrict__ Vc,
                                                   const int* __restrict__ mask_g,
                                                   unsigned short* __restrict__ out) {
    __shared__ __align__(16) unsigned short smK[4096];        // 64 keys x 64 d, swizzled
    __shared__ __align__(16) unsigned short smV[4096];        // 64 d x 64 keys, swizzled
    __shared__ __align__(16) unsigned short smP[4][16 * 72];  // per-wave P [q][key]

    const int t = threadIdx.x;
    const int wave = t >> 6, lane = t & 63;
    const int quad = lane >> 4, l16 = lane & 15;
    const int qt = blockIdx.x, h = blockIdx.y, b = blockIdx.z;
    const int q0 = qt * 64 + wave * 16;
    const unsigned short* Kbh = Kc + ((size_t)(b * NHEAD + h)) * 32 * 4096;
    const unsigned short* Vbh = Vc + ((size_t)(b * NHEAD + h)) * 32 * 4096;
    const int* mrow = mask_g + b * SEQ;
    unsigned short* smPw = &smP[wave][0];

    const unsigned short* Qp = Qb + ((size_t)b * SEQ + q0 + l16) * 1024 + h * HDIM + quad * 8;
    s8v qf0 = *(const s8v*)(Qp);
    s8v qf1 = *(const s8v*)(Qp + 32);

    float l_s = 0.f;
    f4v oacc[4] = {};

    for (int kt = 0; kt < 32; kt++) {
        const int k0 = kt * 64;
        const unsigned short* ks = Kbh + kt * 4096;
        const unsigned short* vs = Vbh + kt * 4096;
        __syncthreads();
        gload_lds16(ks + t * 8,           smK + t * 8);
        gload_lds16(ks + (t + 256) * 8,   smK + (t + 256) * 8);
        gload_lds16(vs + t * 8,           smV + t * 8);
        gload_lds16(vs + (t + 256) * 8,   smV + (t + 256) * 8);
        __syncthreads();

        f4v s[4];
        for (int kt4 = 0; kt4 < 4; kt4++) {
            int r = kt4 * 16 + l16, sw = r & 7;
            s8v kf0 = *(const s8v*)&smK[r * 64 + ((quad ^ sw) * 8)];
            s8v kf1 = *(const s8v*)&smK[r * 64 + (((quad + 4) ^ sw) * 8)];
            f4v z = {};
            z = mfma_bf16(kf0, qf0, z);
            z = mfma_bf16(kf1, qf1, z);
            s[kt4] = z;
        }
        for (int kt4 = 0; kt4 < 4; kt4++) {
            int4 m4 = *(const int4*)&mrow[k0 + kt4 * 16 + quad * 4];
            s[kt4][0] = (m4.x == 0) ? -1e9f : s[kt4][0];
            s[kt4][1] = (m4.y == 0) ? -1e9f : s[kt4][1];
            s[kt4][2] = (m4.z == 0) ? -1e9f : s[kt4][2];
            s[kt4][3] = (m4.w == 0) ? -1e9f : s[kt4][3];
        }
        for (int kt4 = 0; kt4 < 4; kt4++)
            for (int r = 0; r < 4; r++) {
                float p = __expf(s[kt4][r]);
                s[kt4][r] = p;
                l_s += p;
            }
        for (int kt4 = 0; kt4 < 4; kt4++) {
            ushort4 pk;
            pk.x = f2b(s[kt4][0]); pk.y = f2b(s[kt4][1]);
            pk.z = f2b(s[kt4][2]); pk.w = f2b(s[kt4][3]);
            *(ushort4*)&smPw[l16 * 72 + kt4 * 16 + quad * 4] = pk;
        }
        s8v pf0 = *(const s8v*)&smPw[l16 * 72 + quad * 8];
        s8v pf1 = *(const s8v*)&smPw[l16 * 72 + quad * 8 + 32];
        for (int nt = 0; nt < 4; nt++) {
            int r = nt * 16 + l16, sw = r & 7;
            s8v v0 = *(const s8v*)&smV[r * 64 + ((quad ^ sw) * 8)];
            s8v v1 = *(const s8v*)&smV[r * 64 + (((quad + 4) ^ sw) * 8)];
            oacc[nt] = mfma_bf16(pf0, v0, oacc[nt]);
            oacc[nt] = mfma_bf16(pf1, v1, oacc[nt]);
        }
    }

    l_s += __shfl_xor(l_s, 16);
    l_s += __shfl_xor(l_s, 32);
    float lrr[4];
    for (int r = 0; r < 4; r++) lrr[r] = __shfl(l_s, quad * 4 + r);
    for (int nt = 0; nt < 4; nt++)
        for (int r = 0; r < 4; r++) {
            int row = q0 + quad * 4 + r;
            int col = h * HDIM + nt * 16 + l16;
            out[((size_t)b * SEQ + row) * DMODEL + col] = f2b(oacc[nt][r] / lrr[r]);
        }
}

extern "C" void kernel_launch(void* const* d_in, const int* in_sizes, int n_in,
                              void* d_out, int out_size, void* d_ws, size_t ws_size,
                              hipStream_t stream) {
    const float* x   = (const float*)d_in[0];
    const int*   msk = (const int*)d_in[1];
    const float* Wq  = (const float*)d_in[2];
    const float* bq  = (const float*)d_in[3];
    const float* Wk  = (const float*)d_in[4];
    const float* bk  = (const float*)d_in[5];
    const float* Wv  = (const float*)d_in[6];
    const float* bv  = (const float*)d_in[7];
    const float* Wo  = (const float*)d_in[8];
    const float* bo  = (const float*)d_in[9];
    const float* W1  = (const float*)d_in[10];
    const float* b1  = (const float*)d_in[11];
    const float* W2  = (const float*)d_in[12];
    const float* b2  = (const float*)d_in[13];
    const float* a1  = (const float*)d_in[14];
    const float* be1 = (const float*)d_in[15];
    const float* a2  = (const float*)d_in[16];
    const float* be2 = (const float*)d_in[17];
    float* outf = (float*)d_out;   // 4096x1024 fp32 = 16 MB

    // ---- arena (peak 58 MB of ws + d_out reuse) ----
    // ws[ 0, 8)MB : W2_t (ph1-8)
    // ws[ 8,16)MB : W1_t (ph1-7) -> Pbuf fp32 (ph8-9, spans [8,24))
    // ws[16,22)MB : Wqkv_t (ph1-3) -> n2 [16,24) (ph6-7)
    // ws[22,24)MB : bqkv (ph1-3)
    // ws[24,26)MB : Wo_t (ph1-5)
    // ws[26,34)MB : Qb bf16, pre-scaled x0.125 (ph3-4)
    // ws[34,42)MB : Kc packed swizzled (ph3-4, written by qkv epilogue)
    // ws[42,50)MB : Vb bf16 (ph3-3.5)
    // ws[50,58)MB : attnO bf16 (ph4-5)
    // ws[26,58)MB : ff1 32MB (ph7-8)
    // d_out 16MB  : n1 bf16 (ph2-3) -> Vc bf16 [0,8) (ph3.5-4) -> h fp32 (ph5-9)
    char* ws = (char*)d_ws;
    const size_t MB = 1024 * 1024;
    unsigned short* W2_t   = (unsigned short*)(ws);
    unsigned short* W1_t   = (unsigned short*)(ws + 8 * MB);
    float*          Pbuf   = (float*)(ws + 8 * MB);
    unsigned short* Wqkv_t = (unsigned short*)(ws + 16 * MB);
    float*          bqkv   = (float*)(ws + 22 * MB);
    unsigned short* n2     = (unsigned short*)(ws + 16 * MB);
    unsigned short* Wo_t   = (unsigned short*)(ws + 24 * MB);
    unsigned short* Qb     = (unsigned short*)(ws + 26 * MB);
    unsigned short* Kc     = (unsigned short*)(ws + 34 * MB);
    unsigned short* Vb     = (unsigned short*)(ws + 42 * MB);
    unsigned short* ff1    = (unsigned short*)(ws + 26 * MB);
    unsigned short* attnO  = (unsigned short*)(ws + 50 * MB);
    unsigned short* n1     = (unsigned short*)d_out;
    unsigned short* Vc     = (unsigned short*)d_out;
    float*          hbuf   = (float*)d_out;

    // phase 1: all weight transposes + bias concat, single launch
    prep_weights<<<dim3(16, 16, 6), 256, 0, stream>>>(
        Wq, Wk, Wv, Wo, W1, W2, bq, bk, bv, Wqkv_t, Wo_t, W1_t, W2_t, bqkv);

    // phase 2: n1 = LN1(x)  (bf16, in d_out)
    ln_kernel<<<NTOK, 256, 0, stream>>>(x, a1, be1, n1);
    // phase 3: SPLIT3 qkv: Q (x0.125) -> Qb, K -> Kc packed, V -> Vb
    gemm_bt<false, false, unsigned short, true><<<dim3(32, 24), 256, 0, stream>>>(
        n1, Wqkv_t, bqkv, nullptr, Qb, Kc, NTOK, 3072, 1024);
    // phase 3.5: pack V (over dead n1 in d_out)
    pack_v<<<dim3(32, 16, 2), 256, 0, stream>>>(Vb, Vc);
    // phase 4: attention — 64 q/block, 1024 blocks, fixed-max softmax
    attn_kernel<<<dim3(32, 16, 2), 256, 0, stream>>>(Qb, Kc, Vc, msk, attnO);
    // phase 5: h = x + attnO @ Wo^T + bo  (fp32, into d_out; Vc dead)
    gemm_bt<false, true, float><<<dim3(32, 8), 256, 0, stream>>>(
        attnO, Wo_t, bo, x, hbuf, nullptr, NTOK, 1024, 1024);
    // phase 6: n2 = LN2(h)  (bf16, over dead Wqkv_t)
    ln_kernel<<<NTOK, 256, 0, stream>>>(hbuf, a2, be2, n2);
    // phase 7: ff1 = relu(n2 @ W1 + b1)  (bf16, over dead Qb/Kc/Vb/attnO)
    gemm_bt<true, false, unsigned short><<<dim3(32, 32), 256, 0, stream>>>(
        n2, W1_t, b1, nullptr, ff1, nullptr, NTOK, DFF, 1024);
    // phase 8: split-K ff2: z=0 -> out = h + b2 + acc(k<2048); z=1 -> Pbuf = acc(k>=2048)
    ff2_splitk<<<dim3(32, 8, 2), 256, 0, stream>>>(ff1, W2_t, b2, hbuf, outf, Pbuf);
    // phase 9: out += Pbuf
    add_pbuf<<<dim3(2048), 256, 0, stream>>>(outf, Pbuf);
}

// Round 13
// 424.621 us; speedup vs baseline: 2.0421x; 2.0421x over previous
//
#include <hip/hip_runtime.h>

#define SEQ   2048
#define BATCH 2
#define DMODEL 1024
#define DFF   4096
#define NHEAD 16
#define HDIM  64
#define NTOK  (BATCH*SEQ)   // 4096

typedef short s8v __attribute__((ext_vector_type(8)));
typedef float f4v __attribute__((ext_vector_type(4)));

__device__ __forceinline__ float b2f(unsigned short u) {
    union { unsigned int i; float f; } v; v.i = ((unsigned int)u) << 16; return v.f;
}
__device__ __forceinline__ unsigned short f2b(float f) {
    union { unsigned int i; float f; } v; v.f = f;
    unsigned int r = v.i + 0x7FFFu + ((v.i >> 16) & 1u);
    return (unsigned short)(r >> 16);
}

__device__ __forceinline__ f4v mfma_bf16(s8v a, s8v b, f4v c) {
    return __builtin_amdgcn_mfma_f32_16x16x32_bf16(a, b, c, 0, 0, 0);
}

__device__ __forceinline__ void gload_lds16(const void* g, void* l) {
    __builtin_amdgcn_global_load_lds(
        (const __attribute__((address_space(1))) unsigned int*)g,
        (__attribute__((address_space(3))) unsigned int*)l, 16, 0, 0);
}

// ---------------- one tile of fp32->bf16 transpose ----------------
__device__ __forceinline__ void tp_tile(const float* __restrict__ src,
                                        unsigned short* __restrict__ dst,
                                        int R, int C, int br, int bc, int t,
                                        unsigned short* tl) {
    for (int i = 0; i < 16; i++) {
        int idx = t + 256 * i;
        int r = idx >> 6, c = idx & 63;
        tl[r * 65 + c] = f2b(src[(size_t)(br * 64 + r) * C + bc * 64 + c]);
    }
    __syncthreads();
    for (int i = 0; i < 16; i++) {
        int idx = t + 256 * i;
        int r2 = idx >> 6, c2 = idx & 63;
        dst[(size_t)(bc * 64 + r2) * R + br * 64 + c2] = tl[c2 * 65 + r2];
    }
}

// ---------------- fused prep: all 6 weight transposes + bias concat, one launch --------
// grid (16,16,6): z<4 -> 1024x1024 mats; z=4 -> W1 (4 tiles/block); z=5 -> W2 (+ concat)
__global__ __launch_bounds__(256) void prep_weights(const float* __restrict__ Wq,
                                                    const float* __restrict__ Wk,
                                                    const float* __restrict__ Wv,
                                                    const float* __restrict__ Wo,
                                                    const float* __restrict__ W1,
                                                    const float* __restrict__ W2,
                                                    const float* __restrict__ bq,
                                                    const float* __restrict__ bk,
                                                    const float* __restrict__ bv,
                                                    unsigned short* __restrict__ Wqkv_t,
                                                    unsigned short* __restrict__ Wo_t,
                                                    unsigned short* __restrict__ W1_t,
                                                    unsigned short* __restrict__ W2_t,
                                                    float* __restrict__ bqkv) {
    __shared__ unsigned short tl[64 * 65];
    const int t = threadIdx.x;
    const int bx = blockIdx.x, by = blockIdx.y, z = blockIdx.z;
    if (z < 4) {
        const float* src = (z == 0) ? Wq : (z == 1) ? Wk : (z == 2) ? Wv : Wo;
        unsigned short* dst = (z == 3) ? Wo_t : Wqkv_t + (size_t)z * 1024 * 1024;
        tp_tile(src, dst, 1024, 1024, bx, by, t, tl);
    } else if (z == 4) {
        for (int i = 0; i < 4; i++) {
            tp_tile(W1, W1_t, 1024, 4096, bx, by + 16 * i, t, tl);
            __syncthreads();
        }
    } else {
        if (bx == 0 && by == 0) {
            for (int i = 0; i < 12; i++) {
                int idx = t + 256 * i;
                if (idx < 1024) bqkv[idx] = bq[idx];
                else if (idx < 2048) bqkv[idx] = bk[idx - 1024];
                else if (idx < 3072) bqkv[idx] = bv[idx - 2048];
            }
        }
        for (int i = 0; i < 4; i++) {
            tp_tile(W2, W2_t, 4096, 1024, bx + 16 * i, by, t, tl);
            __syncthreads();
        }
    }
}

// ---------------- fused pack K + V (from split blocks, row stride 1024) ----------------
__global__ __launch_bounds__(256) void pack_kv(const unsigned short* __restrict__ Kb,
                                               const unsigned short* __restrict__ Vb,
                                               unsigned short* __restrict__ Kc,
                                               unsigned short* __restrict__ Vc) {
    __shared__ unsigned short tl[64 * 65];
    const int t = threadIdx.x;
    const int kt = blockIdx.x, h = blockIdx.y, b = blockIdx.z;
    const unsigned short* srcK = Kb + (size_t)b * SEQ * 1024 + h * HDIM;
    unsigned short* dstK = Kc + ((size_t)((b * NHEAD + h) * 32 + kt)) * 4096;
    for (int i = 0; i < 2; i++) {
        int ci = t + 256 * i;
        int r = ci >> 3, cp = ci & 7;
        int cl = cp ^ (r & 7);
        *(uint4*)&dstK[ci * 8] = *(const uint4*)&srcK[(size_t)(kt * 64 + r) * 1024 + cl * 8];
    }
    const unsigned short* srcV = Vb + (size_t)b * SEQ * 1024 + h * HDIM;
    for (int i = 0; i < 16; i++) {
        int idx = t + 256 * i;
        int r = idx >> 6, c = idx & 63;      // r = key local, c = d
        tl[r * 65 + c] = srcV[(size_t)(kt * 64 + r) * 1024 + c];
    }
    __syncthreads();
    unsigned short* dstV = Vc + ((size_t)((b * NHEAD + h) * 32 + kt)) * 4096;
    for (int i = 0; i < 2; i++) {
        int ci = t + 256 * i;
        int r = ci >> 3, cp = ci & 7;        // r = d
        int cl = cp ^ (r & 7);
        ushort4 e0, e1;
        e0.x = tl[(cl * 8 + 0) * 65 + r]; e0.y = tl[(cl * 8 + 1) * 65 + r];
        e0.z = tl[(cl * 8 + 2) * 65 + r]; e0.w = tl[(cl * 8 + 3) * 65 + r];
        e1.x = tl[(cl * 8 + 4) * 65 + r]; e1.y = tl[(cl * 8 + 5) * 65 + r];
        e1.z = tl[(cl * 8 + 6) * 65 + r]; e1.w = tl[(cl * 8 + 7) * 65 + r];
        *(ushort4*)&dstV[ci * 8]     = e0;
        *(ushort4*)&dstV[ci * 8 + 4] = e1;
    }
}

// ---------------- layernorm fp32 in -> bf16 out (torch: ddof=1, eps on std) ----------------
__global__ __launch_bounds__(256) void ln_kernel(const float* __restrict__ x,
                                                 const float* __restrict__ al,
                                                 const float* __restrict__ be,
                                                 unsigned short* __restrict__ o) {
    const int row = blockIdx.x;
    const float* xr = x + (size_t)row * DMODEL;
    float4 u = ((const float4*)xr)[threadIdx.x];
    float v[4] = { u.x, u.y, u.z, u.w };
    float s = v[0] + v[1] + v[2] + v[3];
    float sq = v[0]*v[0] + v[1]*v[1] + v[2]*v[2] + v[3]*v[3];
    for (int off = 32; off; off >>= 1) { s += __shfl_xor(s, off); sq += __shfl_xor(sq, off); }
    __shared__ float red[8];
    int wave = threadIdx.x >> 6, lane = threadIdx.x & 63;
    if (!lane) { red[wave] = s; red[4 + wave] = sq; }
    __syncthreads();
    s = red[0] + red[1] + red[2] + red[3];
    sq = red[4] + red[5] + red[6] + red[7];
    float mean = s * (1.f / DMODEL);
    float var = (sq - (float)DMODEL * mean * mean) * (1.f / (DMODEL - 1));
    var = var < 0.f ? 0.f : var;
    float inv = al[0] / (sqrtf(var) + 1e-6f);
    float bt = be[0];
    uint2 ou;
    unsigned short r0 = f2b((v[0] - mean) * inv + bt);
    unsigned short r1 = f2b((v[1] - mean) * inv + bt);
    unsigned short r2 = f2b((v[2] - mean) * inv + bt);
    unsigned short r3 = f2b((v[3] - mean) * inv + bt);
    ou.x = (unsigned int)r0 | ((unsigned int)r1 << 16);
    ou.y = (unsigned int)r2 | ((unsigned int)r3 << 16);
    ((uint2*)(o + (size_t)row * DMODEL))[threadIdx.x] = ou;
}

// ---------------- m97-style GEMM (128x128): C = [relu](A @ Bt^T + bias) [+ res] ----------
// SPLIT3: C cols [0,1024)|[1024,2048)|[2048,3072) land in 3 contiguous [M,1024] blocks.
template<bool RELU, bool RES, typename CT, bool SPLIT3 = false>
__global__ __launch_bounds__(256) void gemm_bt(const unsigned short* __restrict__ A,
                                               const unsigned short* __restrict__ Bt,
                                               const float* __restrict__ bias,
                                               const float* __restrict__ res,
                                               CT* __restrict__ C,
                                               int M, int N, int K) {
    __shared__ __align__(16) unsigned short smA[128 * 32];
    __shared__ __align__(16) unsigned short smB[128 * 32];
    const int t = threadIdx.x;
    const int wave = t >> 6, lane = t & 63;
    const int quad = lane >> 4, l16 = lane & 15;
    const int wm = wave & 1, wn = wave >> 1;
    const int m0 = blockIdx.x * 128, n0 = blockIdx.y * 128;

    f4v acc[4][4] = {};

    const int c0 = t, c1 = t + 256;
    const int rA0 = c0 >> 2, sA0 = c0 & 3;
    const int rA1 = c1 >> 2, sA1 = c1 & 3;

    for (int k0 = 0; k0 < K; k0 += 32) {
        __syncthreads();
        gload_lds16(A  + (size_t)(m0 + rA0) * K + k0 + sA0 * 8, smA + c0 * 8);
        gload_lds16(A  + (size_t)(m0 + rA1) * K + k0 + sA1 * 8, smA + c1 * 8);
        gload_lds16(Bt + (size_t)(n0 + rA0) * K + k0 + sA0 * 8, smB + c0 * 8);
        gload_lds16(Bt + (size_t)(n0 + rA1) * K + k0 + sA1 * 8, smB + c1 * 8);
        __syncthreads();
        s8v a[4], b[4];
        for (int i = 0; i < 4; i++)
            a[i] = *(const s8v*)&smA[(wm * 64 + i * 16 + l16) * 32 + quad * 8];
        for (int i = 0; i < 4; i++)
            b[i] = *(const s8v*)&smB[(wn * 64 + i * 16 + l16) * 32 + quad * 8];
        for (int mi = 0; mi < 4; mi++)
            for (int ni = 0; ni < 4; ni++)
                acc[mi][ni] = mfma_bf16(a[mi], b[ni], acc[mi][ni]);
    }

    for (int mi = 0; mi < 4; mi++) {
        for (int ni = 0; ni < 4; ni++) {
            int col = n0 + wn * 64 + ni * 16 + l16;
            float bv = bias[col];
            for (int r = 0; r < 4; r++) {
                int row = m0 + wm * 64 + mi * 16 + quad * 4 + r;
                float v = acc[mi][ni][r] + bv;
                if (RELU) v = v > 0.f ? v : 0.f;
                if (RES) v += res[(size_t)row * N + col];
                size_t cidx;
                if constexpr (SPLIT3)
                    cidx = (size_t)(col >> 10) * ((size_t)NTOK * 1024)
                         + (size_t)row * 1024 + (col & 1023);
                else
                    cidx = (size_t)row * N + col;
                if constexpr (sizeof(CT) == 2)
                    C[cidx] = f2b(v);
                else
                    C[cidx] = v;
            }
        }
    }
}

// ---------------- ff2 split-K=2 (M=4096, N=1024, K=4096, 128x128 tile) ----------------
__global__ __launch_bounds__(256) void ff2_splitk(const unsigned short* __restrict__ A,
                                                  const unsigned short* __restrict__ Bt,
                                                  const float* __restrict__ bias,
                                                  const float* __restrict__ res,
                                                  float* __restrict__ out,
                                                  float* __restrict__ pbuf) {
    const int K = 4096, N = 1024;
    __shared__ __align__(16) unsigned short smA[128 * 32];
    __shared__ __align__(16) unsigned short smB[128 * 32];
    const int t = threadIdx.x;
    const int wave = t >> 6, lane = t & 63;
    const int quad = lane >> 4, l16 = lane & 15;
    const int wm = wave & 1, wn = wave >> 1;
    const int m0 = blockIdx.x * 128, n0 = blockIdx.y * 128;
    const int z = blockIdx.z;
    const int kbeg = z * 2048, kend = kbeg + 2048;

    f4v acc[4][4] = {};

    const int c0 = t, c1 = t + 256;
    const int rA0 = c0 >> 2, sA0 = c0 & 3;
    const int rA1 = c1 >> 2, sA1 = c1 & 3;

    for (int k0 = kbeg; k0 < kend; k0 += 32) {
        __syncthreads();
        gload_lds16(A  + (size_t)(m0 + rA0) * K + k0 + sA0 * 8, smA + c0 * 8);
        gload_lds16(A  + (size_t)(m0 + rA1) * K + k0 + sA1 * 8, smA + c1 * 8);
        gload_lds16(Bt + (size_t)(n0 + rA0) * K + k0 + sA0 * 8, smB + c0 * 8);
        gload_lds16(Bt + (size_t)(n0 + rA1) * K + k0 + sA1 * 8, smB + c1 * 8);
        __syncthreads();
        s8v a[4], b[4];
        for (int i = 0; i < 4; i++)
            a[i] = *(const s8v*)&smA[(wm * 64 + i * 16 + l16) * 32 + quad * 8];
        for (int i = 0; i < 4; i++)
            b[i] = *(const s8v*)&smB[(wn * 64 + i * 16 + l16) * 32 + quad * 8];
        for (int mi = 0; mi < 4; mi++)
            for (int ni = 0; ni < 4; ni++)
                acc[mi][ni] = mfma_bf16(a[mi], b[ni], acc[mi][ni]);
    }

    for (int mi = 0; mi < 4; mi++) {
        for (int ni = 0; ni < 4; ni++) {
            int col = n0 + wn * 64 + ni * 16 + l16;
            for (int r = 0; r < 4; r++) {
                int row = m0 + wm * 64 + mi * 16 + quad * 4 + r;
                size_t idx = (size_t)row * N + col;
                if (z == 0)
                    out[idx] = acc[mi][ni][r] + bias[col] + res[idx];
                else
                    pbuf[idx] = acc[mi][ni][r];
            }
        }
    }
}

// ---------------- combine: out += Pbuf ----------------
__global__ __launch_bounds__(256) void add_pbuf(float* __restrict__ out,
                                                const float* __restrict__ pbuf) {
    const int i0 = (blockIdx.x * 256 + threadIdx.x) * 8;
    float4 a0 = *(const float4*)&out[i0];
    float4 a1 = *(const float4*)&out[i0 + 4];
    float4 p0 = *(const float4*)&pbuf[i0];
    float4 p1 = *(const float4*)&pbuf[i0 + 4];
    a0.x += p0.x; a0.y += p0.y; a0.z += p0.z; a0.w += p0.w;
    a1.x += p1.x; a1.y += p1.y; a1.z += p1.z; a1.w += p1.w;
    *(float4*)&out[i0]     = a0;
    *(float4*)&out[i0 + 4] = a1;
}

// ---------------- flash attention: 64 q/block, fixed-max softmax (exp(s), no rescale) ---
// Valid because LN'd q keeps |s| << 88 (fp32 exp range) and masked s = -1e9 -> exp = 0.
__global__ __launch_bounds__(256) void attn_kernel(const unsigned short* __restrict__ Qb,
                                                   const unsigned short* __restrict__ Kc,
                                                   const unsigned short* __restrict__ Vc,
                                                   const int* __restrict__ mask_g,
                                                   unsigned short* __restrict__ out) {
    __shared__ __align__(16) unsigned short smK[4096];        // 64 keys x 64 d, swizzled
    __shared__ __align__(16) unsigned short smV[4096];        // 64 d x 64 keys, swizzled
    __shared__ __align__(16) unsigned short smP[4][16 * 72];  // per-wave P [q][key]

    const int t = threadIdx.x;
    const int wave = t >> 6, lane = t & 63;
    const int quad = lane >> 4, l16 = lane & 15;
    const int qt = blockIdx.x, h = blockIdx.y, b = blockIdx.z;
    const int q0 = qt * 64 + wave * 16;
    const unsigned short* Kbh = Kc + ((size_t)(b * NHEAD + h)) * 32 * 4096;
    const unsigned short* Vbh = Vc + ((size_t)(b * NHEAD + h)) * 32 * 4096;
    const int* mrow = mask_g + b * SEQ;
    unsigned short* smPw = &smP[wave][0];

    const unsigned short* Qp = Qb + ((size_t)b * SEQ + q0 + l16) * 1024 + h * HDIM + quad * 8;
    s8v qf0 = *(const s8v*)(Qp);
    s8v qf1 = *(const s8v*)(Qp + 32);

    float l_s = 0.f;
    f4v oacc[4] = {};

    for (int kt = 0; kt < 32; kt++) {
        const int k0 = kt * 64;
        const unsigned short* ks = Kbh + kt * 4096;
        const unsigned short* vs = Vbh + kt * 4096;
        __syncthreads();
        gload_lds16(ks + t * 8,           smK + t * 8);
        gload_lds16(ks + (t + 256) * 8,   smK + (t + 256) * 8);
        gload_lds16(vs + t * 8,           smV + t * 8);
        gload_lds16(vs + (t + 256) * 8,   smV + (t + 256) * 8);
        __syncthreads();

        f4v s[4];
        for (int kt4 = 0; kt4 < 4; kt4++) {
            int r = kt4 * 16 + l16, sw = r & 7;
            s8v kf0 = *(const s8v*)&smK[r * 64 + ((quad ^ sw) * 8)];
            s8v kf1 = *(const s8v*)&smK[r * 64 + (((quad + 4) ^ sw) * 8)];
            f4v z = {};
            z = mfma_bf16(kf0, qf0, z);
            z = mfma_bf16(kf1, qf1, z);
            s[kt4] = z;
        }
        for (int kt4 = 0; kt4 < 4; kt4++) {
            int4 m4 = *(const int4*)&mrow[k0 + kt4 * 16 + quad * 4];
            s[kt4][0] = (m4.x == 0) ? -1e9f : s[kt4][0] * 0.125f;
            s[kt4][1] = (m4.y == 0) ? -1e9f : s[kt4][1] * 0.125f;
            s[kt4][2] = (m4.z == 0) ? -1e9f : s[kt4][2] * 0.125f;
            s[kt4][3] = (m4.w == 0) ? -1e9f : s[kt4][3] * 0.125f;
        }
        for (int kt4 = 0; kt4 < 4; kt4++)
            for (int r = 0; r < 4; r++) {
                float p = __expf(s[kt4][r]);
                s[kt4][r] = p;
                l_s += p;
            }
        for (int kt4 = 0; kt4 < 4; kt4++) {
            ushort4 pk;
            pk.x = f2b(s[kt4][0]); pk.y = f2b(s[kt4][1]);
            pk.z = f2b(s[kt4][2]); pk.w = f2b(s[kt4][3]);
            *(ushort4*)&smPw[l16 * 72 + kt4 * 16 + quad * 4] = pk;
        }
        s8v pf0 = *(const s8v*)&smPw[l16 * 72 + quad * 8];
        s8v pf1 = *(const s8v*)&smPw[l16 * 72 + quad * 8 + 32];
        for (int nt = 0; nt < 4; nt++) {
            int r = nt * 16 + l16, sw = r & 7;
            s8v v0 = *(const s8v*)&smV[r * 64 + ((quad ^ sw) * 8)];
            s8v v1 = *(const s8v*)&smV[r * 64 + (((quad + 4) ^ sw) * 8)];
            oacc[nt] = mfma_bf16(pf0, v0, oacc[nt]);
            oacc[nt] = mfma_bf16(pf1, v1, oacc[nt]);
        }
    }

    l_s += __shfl_xor(l_s, 16);
    l_s += __shfl_xor(l_s, 32);
    float lrr[4];
    for (int r = 0; r < 4; r++) lrr[r] = __shfl(l_s, quad * 4 + r);
    for (int nt = 0; nt < 4; nt++)
        for (int r = 0; r < 4; r++) {
            int row = q0 + quad * 4 + r;
            int col = h * HDIM + nt * 16 + l16;
            out[((size_t)b * SEQ + row) * DMODEL + col] = f2b(oacc[nt][r] / lrr[r]);
        }
}

extern "C" void kernel_launch(void* const* d_in, const int* in_sizes, int n_in,
                              void* d_out, int out_size, void* d_ws, size_t ws_size,
                              hipStream_t stream) {
    const float* x   = (const float*)d_in[0];
    const int*   msk = (const int*)d_in[1];
    const float* Wq  = (const float*)d_in[2];
    const float* bq  = (const float*)d_in[3];
    const float* Wk  = (const float*)d_in[4];
    const float* bk  = (const float*)d_in[5];
    const float* Wv  = (const float*)d_in[6];
    const float* bv  = (const float*)d_in[7];
    const float* Wo  = (const float*)d_in[8];
    const float* bo  = (const float*)d_in[9];
    const float* W1  = (const float*)d_in[10];
    const float* b1  = (const float*)d_in[11];
    const float* W2  = (const float*)d_in[12];
    const float* b2  = (const float*)d_in[13];
    const float* a1  = (const float*)d_in[14];
    const float* be1 = (const float*)d_in[15];
    const float* a2  = (const float*)d_in[16];
    const float* be2 = (const float*)d_in[17];
    float* outf = (float*)d_out;   // 4096x1024 fp32 = 16 MB

    // ---- arena (peak 58 MB of ws + d_out reuse) — identical to R11 ----
    char* ws = (char*)d_ws;
    const size_t MB = 1024 * 1024;
    unsigned short* W2_t   = (unsigned short*)(ws);
    unsigned short* W1_t   = (unsigned short*)(ws + 8 * MB);
    float*          Pbuf   = (float*)(ws + 8 * MB);
    unsigned short* Wqkv_t = (unsigned short*)(ws + 16 * MB);
    float*          bqkv   = (float*)(ws + 22 * MB);
    unsigned short* Kc     = (unsigned short*)(ws + 16 * MB);
    unsigned short* n2     = (unsigned short*)(ws + 16 * MB);
    unsigned short* Wo_t   = (unsigned short*)(ws + 24 * MB);
    unsigned short* Qb     = (unsigned short*)(ws + 26 * MB);
    unsigned short* Kb     = (unsigned short*)(ws + 34 * MB);
    unsigned short* Vb     = (unsigned short*)(ws + 42 * MB);
    unsigned short* ff1    = (unsigned short*)(ws + 26 * MB);
    unsigned short* attnO  = (unsigned short*)(ws + 50 * MB);
    unsigned short* n1     = (unsigned short*)d_out;
    unsigned short* Vc     = (unsigned short*)d_out;
    float*          hbuf   = (float*)d_out;

    // phase 1: all weight transposes + bias concat, single launch
    prep_weights<<<dim3(16, 16, 6), 256, 0, stream>>>(
        Wq, Wk, Wv, Wo, W1, W2, bq, bk, bv, Wqkv_t, Wo_t, W1_t, W2_t, bqkv);

    // phase 2: n1 = LN1(x)  (bf16, in d_out)
    ln_kernel<<<NTOK, 256, 0, stream>>>(x, a1, be1, n1);
    // phase 3: [Q|K|V] = n1 @ Wqkv + bias, 3 contiguous blocks (SPLIT3, branchless)
    gemm_bt<false, false, unsigned short, true><<<dim3(32, 24), 256, 0, stream>>>(
        n1, Wqkv_t, bqkv, nullptr, Qb, NTOK, 3072, 1024);
    // phase 3.5: pack K (over dead Wqkv_t/bqkv) + V (over dead n1 in d_out)
    pack_kv<<<dim3(32, 16, 2), 256, 0, stream>>>(Kb, Vb, Kc, Vc);
    // phase 4: attention — 64 q/block, 1024 blocks, fixed-max softmax
    attn_kernel<<<dim3(32, 16, 2), 256, 0, stream>>>(Qb, Kc, Vc, msk, attnO);
    // phase 5: h = x + attnO @ Wo^T + bo  (fp32, into d_out; Vc dead)
    gemm_bt<false, true, float><<<dim3(32, 8), 256, 0, stream>>>(
        attnO, Wo_t, bo, x, hbuf, NTOK, 1024, 1024);
    // phase 6: n2 = LN2(h)  (bf16, over dead Kc)
    ln_kernel<<<NTOK, 256, 0, stream>>>(hbuf, a2, be2, n2);
    // phase 7: ff1 = relu(n2 @ W1 + b1)  (bf16, over dead Qb/Kb/Vb/attnO)
    gemm_bt<true, false, unsigned short><<<dim3(32, 32), 256, 0, stream>>>(
        n2, W1_t, b1, nullptr, ff1, NTOK, DFF, 1024);
    // phase 8: split-K ff2: z=0 -> out = h + b2 + acc(k<2048); z=1 -> Pbuf = acc(k>=2048)
    ff2_splitk<<<dim3(32, 8, 2), 256, 0, stream>>>(ff1, W2_t, b2, hbuf, outf, Pbuf);
    // phase 9: out += Pbuf
    add_pbuf<<<dim3(2048), 256, 0, stream>>>(outf, Pbuf);
}

// Round 14
// 415.117 us; speedup vs baseline: 2.0888x; 1.0229x over previous
//
#include <hip/hip_runtime.h>
#include <hip/hip_bf16.h>

#define SEQ   2048
#define BATCH 2
#define DMODEL 1024
#define DFF   4096
#define NHEAD 16
#define HDIM  64
#define NTOK  (BATCH*SEQ)   // 4096

typedef short s8v __attribute__((ext_vector_type(8)));
typedef float f4v __attribute__((ext_vector_type(4)));

__device__ __forceinline__ float b2f(unsigned short u) {
    union { unsigned int i; float f; } v; v.i = ((unsigned int)u) << 16; return v.f;
}
__device__ __forceinline__ unsigned short f2b(float f) {
    union { unsigned int i; float f; } v; v.f = f;
    unsigned int r = v.i + 0x7FFFu + ((v.i >> 16) & 1u);
    return (unsigned short)(r >> 16);
}
__device__ __forceinline__ ushort2 cvt_pk(float a, float b) {
    __hip_bfloat162 h = __float22bfloat162_rn(float2{ a, b });   // RNE, same as f2b
    return *(ushort2*)&h;
}

__device__ __forceinline__ f4v mfma_bf16(s8v a, s8v b, f4v c) {
    return __builtin_amdgcn_mfma_f32_16x16x32_bf16(a, b, c, 0, 0, 0);
}

__device__ __forceinline__ void gload_lds16(const void* g, void* l) {
    __builtin_amdgcn_global_load_lds(
        (const __attribute__((address_space(1))) unsigned int*)g,
        (__attribute__((address_space(3))) unsigned int*)l, 16, 0, 0);
}

// ---------------- one tile of fp32->bf16 transpose ----------------
__device__ __forceinline__ void tp_tile(const float* __restrict__ src,
                                        unsigned short* __restrict__ dst,
                                        int R, int C, int br, int bc, int t,
                                        unsigned short* tl) {
    for (int i = 0; i < 16; i++) {
        int idx = t + 256 * i;
        int r = idx >> 6, c = idx & 63;
        tl[r * 65 + c] = f2b(src[(size_t)(br * 64 + r) * C + bc * 64 + c]);
    }
    __syncthreads();
    for (int i = 0; i < 16; i++) {
        int idx = t + 256 * i;
        int r2 = idx >> 6, c2 = idx & 63;
        dst[(size_t)(bc * 64 + r2) * R + br * 64 + c2] = tl[c2 * 65 + r2];
    }
}

// ---------------- fused prep: weight transposes + bias concat + maskf + LN1 ------------
// grid (16,16,22): z<4 -> 1024x1024 mats; z=4 -> W1; z=5 -> W2 (+ concat + maskf);
// z>=6 -> LN1 rows (row = (z-6)*256 + by*16 + bx)
__global__ __launch_bounds__(256) void prep_weights(const float* __restrict__ Wq,
                                                    const float* __restrict__ Wk,
                                                    const float* __restrict__ Wv,
                                                    const float* __restrict__ Wo,
                                                    const float* __restrict__ W1,
                                                    const float* __restrict__ W2,
                                                    const float* __restrict__ bq,
                                                    const float* __restrict__ bk,
                                                    const float* __restrict__ bv,
                                                    const int* __restrict__ msk,
                                                    const float* __restrict__ x,
                                                    const float* __restrict__ a1,
                                                    const float* __restrict__ be1,
                                                    unsigned short* __restrict__ Wqkv_t,
                                                    unsigned short* __restrict__ Wo_t,
                                                    unsigned short* __restrict__ W1_t,
                                                    unsigned short* __restrict__ W2_t,
                                                    float* __restrict__ bqkv,
                                                    float* __restrict__ maskf,
                                                    unsigned short* __restrict__ n1) {
    __shared__ unsigned short tl[64 * 65];
    __shared__ float red[8];
    const int t = threadIdx.x;
    const int bx = blockIdx.x, by = blockIdx.y, z = blockIdx.z;
    if (z < 4) {
        const float* src = (z == 0) ? Wq : (z == 1) ? Wk : (z == 2) ? Wv : Wo;
        unsigned short* dst = (z == 3) ? Wo_t : Wqkv_t + (size_t)z * 1024 * 1024;
        tp_tile(src, dst, 1024, 1024, bx, by, t, tl);
    } else if (z == 4) {
        for (int i = 0; i < 4; i++) {
            tp_tile(W1, W1_t, 1024, 4096, bx, by + 16 * i, t, tl);
            __syncthreads();
        }
    } else if (z == 5) {
        if (bx == 0 && by == 0) {
            for (int i = 0; i < 12; i++) {
                int idx = t + 256 * i;
                if (idx < 1024) bqkv[idx] = bq[idx];
                else if (idx < 2048) bqkv[idx] = bk[idx - 1024];
                else if (idx < 3072) bqkv[idx] = bv[idx - 2048];
            }
        }
        if (bx == 1 && by == 0) {
            for (int i = 0; i < 16; i++) {
                int idx = t + 256 * i;     // BATCH*SEQ = 4096
                maskf[idx] = (msk[idx] == 0) ? -1e9f : 0.f;
            }
        }
        for (int i = 0; i < 4; i++) {
            tp_tile(W2, W2_t, 4096, 1024, bx + 16 * i, by, t, tl);
            __syncthreads();
        }
    } else {
        // LN1: one row per block
        const int row = (z - 6) * 256 + by * 16 + bx;
        const float* xr = x + (size_t)row * DMODEL;
        float4 u = ((const float4*)xr)[t];
        float v[4] = { u.x, u.y, u.z, u.w };
        float s = v[0] + v[1] + v[2] + v[3];
        float sq = v[0]*v[0] + v[1]*v[1] + v[2]*v[2] + v[3]*v[3];
        for (int off = 32; off; off >>= 1) { s += __shfl_xor(s, off); sq += __shfl_xor(sq, off); }
        int wave = t >> 6, lane = t & 63;
        if (!lane) { red[wave] = s; red[4 + wave] = sq; }
        __syncthreads();
        s = red[0] + red[1] + red[2] + red[3];
        sq = red[4] + red[5] + red[6] + red[7];
        float mean = s * (1.f / DMODEL);
        float var = (sq - (float)DMODEL * mean * mean) * (1.f / (DMODEL - 1));
        var = var < 0.f ? 0.f : var;
        float inv = a1[0] / (sqrtf(var) + 1e-6f);
        float bt = be1[0];
        uint2 ou;
        unsigned short r0 = f2b((v[0] - mean) * inv + bt);
        unsigned short r1 = f2b((v[1] - mean) * inv + bt);
        unsigned short r2 = f2b((v[2] - mean) * inv + bt);
        unsigned short r3 = f2b((v[3] - mean) * inv + bt);
        ou.x = (unsigned int)r0 | ((unsigned int)r1 << 16);
        ou.y = (unsigned int)r2 | ((unsigned int)r3 << 16);
        ((uint2*)(n1 + (size_t)row * DMODEL))[t] = ou;
    }
}

// ---------------- fused pack K + V (from split blocks, row stride 1024) ----------------
__global__ __launch_bounds__(256) void pack_kv(const unsigned short* __restrict__ Kb,
                                               const unsigned short* __restrict__ Vb,
                                               unsigned short* __restrict__ Kc,
                                               unsigned short* __restrict__ Vc) {
    __shared__ unsigned short tl[64 * 65];
    const int t = threadIdx.x;
    const int kt = blockIdx.x, h = blockIdx.y, b = blockIdx.z;
    const unsigned short* srcK = Kb + (size_t)b * SEQ * 1024 + h * HDIM;
    unsigned short* dstK = Kc + ((size_t)((b * NHEAD + h) * 32 + kt)) * 4096;
    for (int i = 0; i < 2; i++) {
        int ci = t + 256 * i;
        int r = ci >> 3, cp = ci & 7;
        int cl = cp ^ (r & 7);
        *(uint4*)&dstK[ci * 8] = *(const uint4*)&srcK[(size_t)(kt * 64 + r) * 1024 + cl * 8];
    }
    const unsigned short* srcV = Vb + (size_t)b * SEQ * 1024 + h * HDIM;
    for (int i = 0; i < 16; i++) {
        int idx = t + 256 * i;
        int r = idx >> 6, c = idx & 63;      // r = key local, c = d
        tl[r * 65 + c] = srcV[(size_t)(kt * 64 + r) * 1024 + c];
    }
    __syncthreads();
    unsigned short* dstV = Vc + ((size_t)((b * NHEAD + h) * 32 + kt)) * 4096;
    for (int i = 0; i < 2; i++) {
        int ci = t + 256 * i;
        int r = ci >> 3, cp = ci & 7;        // r = d
        int cl = cp ^ (r & 7);
        ushort4 e0, e1;
        e0.x = tl[(cl * 8 + 0) * 65 + r]; e0.y = tl[(cl * 8 + 1) * 65 + r];
        e0.z = tl[(cl * 8 + 2) * 65 + r]; e0.w = tl[(cl * 8 + 3) * 65 + r];
        e1.x = tl[(cl * 8 + 4) * 65 + r]; e1.y = tl[(cl * 8 + 5) * 65 + r];
        e1.z = tl[(cl * 8 + 6) * 65 + r]; e1.w = tl[(cl * 8 + 7) * 65 + r];
        *(ushort4*)&dstV[ci * 8]     = e0;
        *(ushort4*)&dstV[ci * 8 + 4] = e1;
    }
}

// ---------------- layernorm fp32 in -> bf16 out (torch: ddof=1, eps on std) ----------------
__global__ __launch_bounds__(256) void ln_kernel(const float* __restrict__ x,
                                                 const float* __restrict__ al,
                                                 const float* __restrict__ be,
                                                 unsigned short* __restrict__ o) {
    const int row = blockIdx.x;
    const float* xr = x + (size_t)row * DMODEL;
    float4 u = ((const float4*)xr)[threadIdx.x];
    float v[4] = { u.x, u.y, u.z, u.w };
    float s = v[0] + v[1] + v[2] + v[3];
    float sq = v[0]*v[0] + v[1]*v[1] + v[2]*v[2] + v[3]*v[3];
    for (int off = 32; off; off >>= 1) { s += __shfl_xor(s, off); sq += __shfl_xor(sq, off); }
    __shared__ float red[8];
    int wave = threadIdx.x >> 6, lane = threadIdx.x & 63;
    if (!lane) { red[wave] = s; red[4 + wave] = sq; }
    __syncthreads();
    s = red[0] + red[1] + red[2] + red[3];
    sq = red[4] + red[5] + red[6] + red[7];
    float mean = s * (1.f / DMODEL);
    float var = (sq - (float)DMODEL * mean * mean) * (1.f / (DMODEL - 1));
    var = var < 0.f ? 0.f : var;
    float inv = al[0] / (sqrtf(var) + 1e-6f);
    float bt = be[0];
    uint2 ou;
    unsigned short r0 = f2b((v[0] - mean) * inv + bt);
    unsigned short r1 = f2b((v[1] - mean) * inv + bt);
    unsigned short r2 = f2b((v[2] - mean) * inv + bt);
    unsigned short r3 = f2b((v[3] - mean) * inv + bt);
    ou.x = (unsigned int)r0 | ((unsigned int)r1 << 16);
    ou.y = (unsigned int)r2 | ((unsigned int)r3 << 16);
    ((uint2*)(o + (size_t)row * DMODEL))[threadIdx.x] = ou;
}

// ---------------- m97-style GEMM (128x128): C = [relu](A @ Bt^T + bias) [+ res] ----------
// SPLIT3: C cols [0,1024)|[1024,2048)|[2048,3072) land in 3 contiguous [M,1024] blocks.
template<bool RELU, bool RES, typename CT, bool SPLIT3 = false>
__global__ __launch_bounds__(256) void gemm_bt(const unsigned short* __restrict__ A,
                                               const unsigned short* __restrict__ Bt,
                                               const float* __restrict__ bias,
                                               const float* __restrict__ res,
                                               CT* __restrict__ C,
                                               int M, int N, int K) {
    __shared__ __align__(16) unsigned short smA[128 * 32];
    __shared__ __align__(16) unsigned short smB[128 * 32];
    const int t = threadIdx.x;
    const int wave = t >> 6, lane = t & 63;
    const int quad = lane >> 4, l16 = lane & 15;
    const int wm = wave & 1, wn = wave >> 1;
    const int m0 = blockIdx.x * 128, n0 = blockIdx.y * 128;

    f4v acc[4][4] = {};

    const int c0 = t, c1 = t + 256;
    const int rA0 = c0 >> 2, sA0 = c0 & 3;
    const int rA1 = c1 >> 2, sA1 = c1 & 3;

    for (int k0 = 0; k0 < K; k0 += 32) {
        __syncthreads();
        gload_lds16(A  + (size_t)(m0 + rA0) * K + k0 + sA0 * 8, smA + c0 * 8);
        gload_lds16(A  + (size_t)(m0 + rA1) * K + k0 + sA1 * 8, smA + c1 * 8);
        gload_lds16(Bt + (size_t)(n0 + rA0) * K + k0 + sA0 * 8, smB + c0 * 8);
        gload_lds16(Bt + (size_t)(n0 + rA1) * K + k0 + sA1 * 8, smB + c1 * 8);
        __syncthreads();
        s8v a[4], b[4];
        for (int i = 0; i < 4; i++)
            a[i] = *(const s8v*)&smA[(wm * 64 + i * 16 + l16) * 32 + quad * 8];
        for (int i = 0; i < 4; i++)
            b[i] = *(const s8v*)&smB[(wn * 64 + i * 16 + l16) * 32 + quad * 8];
        for (int mi = 0; mi < 4; mi++)
            for (int ni = 0; ni < 4; ni++)
                acc[mi][ni] = mfma_bf16(a[mi], b[ni], acc[mi][ni]);
    }

    for (int mi = 0; mi < 4; mi++) {
        for (int ni = 0; ni < 4; ni++) {
            int col = n0 + wn * 64 + ni * 16 + l16;
            float bv = bias[col];
            for (int r = 0; r < 4; r++) {
                int row = m0 + wm * 64 + mi * 16 + quad * 4 + r;
                float v = acc[mi][ni][r] + bv;
                if (RELU) v = v > 0.f ? v : 0.f;
                if (RES) v += res[(size_t)row * N + col];
                size_t cidx;
                if constexpr (SPLIT3)
                    cidx = (size_t)(col >> 10) * ((size_t)NTOK * 1024)
                         + (size_t)row * 1024 + (col & 1023);
                else
                    cidx = (size_t)row * N + col;
                if constexpr (sizeof(CT) == 2)
                    C[cidx] = f2b(v);
                else
                    C[cidx] = v;
            }
        }
    }
}

// ---------------- ff2 split-K=2 (M=4096, N=1024, K=4096, 128x128 tile) ----------------
__global__ __launch_bounds__(256) void ff2_splitk(const unsigned short* __restrict__ A,
                                                  const unsigned short* __restrict__ Bt,
                                                  const float* __restrict__ bias,
                                                  const float* __restrict__ res,
                                                  float* __restrict__ out,
                                                  float* __restrict__ pbuf) {
    const int K = 4096, N = 1024;
    __shared__ __align__(16) unsigned short smA[128 * 32];
    __shared__ __align__(16) unsigned short smB[128 * 32];
    const int t = threadIdx.x;
    const int wave = t >> 6, lane = t & 63;
    const int quad = lane >> 4, l16 = lane & 15;
    const int wm = wave & 1, wn = wave >> 1;
    const int m0 = blockIdx.x * 128, n0 = blockIdx.y * 128;
    const int z = blockIdx.z;
    const int kbeg = z * 2048, kend = kbeg + 2048;

    f4v acc[4][4] = {};

    const int c0 = t, c1 = t + 256;
    const int rA0 = c0 >> 2, sA0 = c0 & 3;
    const int rA1 = c1 >> 2, sA1 = c1 & 3;

    for (int k0 = kbeg; k0 < kend; k0 += 32) {
        __syncthreads();
        gload_lds16(A  + (size_t)(m0 + rA0) * K + k0 + sA0 * 8, smA + c0 * 8);
        gload_lds16(A  + (size_t)(m0 + rA1) * K + k0 + sA1 * 8, smA + c1 * 8);
        gload_lds16(Bt + (size_t)(n0 + rA0) * K + k0 + sA0 * 8, smB + c0 * 8);
        gload_lds16(Bt + (size_t)(n0 + rA1) * K + k0 + sA1 * 8, smB + c1 * 8);
        __syncthreads();
        s8v a[4], b[4];
        for (int i = 0; i < 4; i++)
            a[i] = *(const s8v*)&smA[(wm * 64 + i * 16 + l16) * 32 + quad * 8];
        for (int i = 0; i < 4; i++)
            b[i] = *(const s8v*)&smB[(wn * 64 + i * 16 + l16) * 32 + quad * 8];
        for (int mi = 0; mi < 4; mi++)
            for (int ni = 0; ni < 4; ni++)
                acc[mi][ni] = mfma_bf16(a[mi], b[ni], acc[mi][ni]);
    }

    for (int mi = 0; mi < 4; mi++) {
        for (int ni = 0; ni < 4; ni++) {
            int col = n0 + wn * 64 + ni * 16 + l16;
            for (int r = 0; r < 4; r++) {
                int row = m0 + wm * 64 + mi * 16 + quad * 4 + r;
                size_t idx = (size_t)row * N + col;
                if (z == 0)
                    out[idx] = acc[mi][ni][r] + bias[col] + res[idx];
                else
                    pbuf[idx] = acc[mi][ni][r];
            }
        }
    }
}

// ---------------- combine: out += Pbuf ----------------
__global__ __launch_bounds__(256) void add_pbuf(float* __restrict__ out,
                                                const float* __restrict__ pbuf) {
    const int i0 = (blockIdx.x * 256 + threadIdx.x) * 8;
    float4 a0 = *(const float4*)&out[i0];
    float4 a1 = *(const float4*)&out[i0 + 4];
    float4 p0 = *(const float4*)&pbuf[i0];
    float4 p1 = *(const float4*)&pbuf[i0 + 4];
    a0.x += p0.x; a0.y += p0.y; a0.z += p0.z; a0.w += p0.w;
    a1.x += p1.x; a1.y += p1.y; a1.z += p1.z; a1.w += p1.w;
    *(float4*)&out[i0]     = a0;
    *(float4*)&out[i0 + 4] = a1;
}

// ---------------- flash attention: 64 q/block, fixed-max softmax, fma-mask -------------
// maskf = 0 or -1e9 per key; s*0.125 + maskf then exp -> masked lanes exactly 0 in fp32.
__global__ __launch_bounds__(256) void attn_kernel(const unsigned short* __restrict__ Qb,
                                                   const unsigned short* __restrict__ Kc,
                                                   const unsigned short* __restrict__ Vc,
                                                   const float* __restrict__ maskf,
                                                   unsigned short* __restrict__ out) {
    __shared__ __align__(16) unsigned short smK[4096];        // 64 keys x 64 d, swizzled
    __shared__ __align__(16) unsigned short smV[4096];        // 64 d x 64 keys, swizzled
    __shared__ __align__(16) unsigned short smP[4][16 * 72];  // per-wave P [q][key]

    const int t = threadIdx.x;
    const int wave = t >> 6, lane = t & 63;
    const int quad = lane >> 4, l16 = lane & 15;
    const int qt = blockIdx.x, h = blockIdx.y, b = blockIdx.z;
    const int q0 = qt * 64 + wave * 16;
    const unsigned short* Kbh = Kc + ((size_t)(b * NHEAD + h)) * 32 * 4096;
    const unsigned short* Vbh = Vc + ((size_t)(b * NHEAD + h)) * 32 * 4096;
    const float* mrow = maskf + b * SEQ;
    unsigned short* smPw = &smP[wave][0];

    const unsigned short* Qp = Qb + ((size_t)b * SEQ + q0 + l16) * 1024 + h * HDIM + quad * 8;
    s8v qf0 = *(const s8v*)(Qp);
    s8v qf1 = *(const s8v*)(Qp + 32);

    float l_s = 0.f;
    f4v oacc[4] = {};

    for (int kt = 0; kt < 32; kt++) {
        const int k0 = kt * 64;
        const unsigned short* ks = Kbh + kt * 4096;
        const unsigned short* vs = Vbh + kt * 4096;
        __syncthreads();
        gload_lds16(ks + t * 8,           smK + t * 8);
        gload_lds16(ks + (t + 256) * 8,   smK + (t + 256) * 8);
        gload_lds16(vs + t * 8,           smV + t * 8);
        gload_lds16(vs + (t + 256) * 8,   smV + (t + 256) * 8);
        __syncthreads();

        f4v s[4];
        for (int kt4 = 0; kt4 < 4; kt4++) {
            int r = kt4 * 16 + l16, sw = r & 7;
            s8v kf0 = *(const s8v*)&smK[r * 64 + ((quad ^ sw) * 8)];
            s8v kf1 = *(const s8v*)&smK[r * 64 + (((quad + 4) ^ sw) * 8)];
            f4v z = {};
            z = mfma_bf16(kf0, qf0, z);
            z = mfma_bf16(kf1, qf1, z);
            s[kt4] = z;
        }
        // scale+mask via fma, exp with fixed max 0, accumulate denom per-lane
        for (int kt4 = 0; kt4 < 4; kt4++) {
            float4 mf = *(const float4*)&mrow[k0 + kt4 * 16 + quad * 4];
            s[kt4][0] = s[kt4][0] * 0.125f + mf.x;
            s[kt4][1] = s[kt4][1] * 0.125f + mf.y;
            s[kt4][2] = s[kt4][2] * 0.125f + mf.z;
            s[kt4][3] = s[kt4][3] * 0.125f + mf.w;
        }
        for (int kt4 = 0; kt4 < 4; kt4++)
            for (int r = 0; r < 4; r++) {
                float p = __expf(s[kt4][r]);
                s[kt4][r] = p;
                l_s += p;
            }
        // P store with packed bf16 cvt (RNE)
        for (int kt4 = 0; kt4 < 4; kt4++) {
            ushort2 p01 = cvt_pk(s[kt4][0], s[kt4][1]);
            ushort2 p23 = cvt_pk(s[kt4][2], s[kt4][3]);
            ushort4 pk;
            pk.x = p01.x; pk.y = p01.y; pk.z = p23.x; pk.w = p23.y;
            *(ushort4*)&smPw[l16 * 72 + kt4 * 16 + quad * 4] = pk;
        }
        s8v pf0 = *(const s8v*)&smPw[l16 * 72 + quad * 8];
        s8v pf1 = *(const s8v*)&smPw[l16 * 72 + quad * 8 + 32];
        for (int nt = 0; nt < 4; nt++) {
            int r = nt * 16 + l16, sw = r & 7;
            s8v v0 = *(const s8v*)&smV[r * 64 + ((quad ^ sw) * 8)];
            s8v v1 = *(const s8v*)&smV[r * 64 + (((quad + 4) ^ sw) * 8)];
            oacc[nt] = mfma_bf16(pf0, v0, oacc[nt]);
            oacc[nt] = mfma_bf16(pf1, v1, oacc[nt]);
        }
    }

    l_s += __shfl_xor(l_s, 16);
    l_s += __shfl_xor(l_s, 32);
    float lrr[4];
    for (int r = 0; r < 4; r++) lrr[r] = __shfl(l_s, quad * 4 + r);
    for (int nt = 0; nt < 4; nt++)
        for (int r = 0; r < 4; r++) {
            int row = q0 + quad * 4 + r;
            int col = h * HDIM + nt * 16 + l16;
            out[((size_t)b * SEQ + row) * DMODEL + col] = f2b(oacc[nt][r] / lrr[r]);
        }
}

extern "C" void kernel_launch(void* const* d_in, const int* in_sizes, int n_in,
                              void* d_out, int out_size, void* d_ws, size_t ws_size,
                              hipStream_t stream) {
    const float* x   = (const float*)d_in[0];
    const int*   msk = (const int*)d_in[1];
    const float* Wq  = (const float*)d_in[2];
    const float* bq  = (const float*)d_in[3];
    const float* Wk  = (const float*)d_in[4];
    const float* bk  = (const float*)d_in[5];
    const float* Wv  = (const float*)d_in[6];
    const float* bv  = (const float*)d_in[7];
    const float* Wo  = (const float*)d_in[8];
    const float* bo  = (const float*)d_in[9];
    const float* W1  = (const float*)d_in[10];
    const float* b1  = (const float*)d_in[11];
    const float* W2  = (const float*)d_in[12];
    const float* b2  = (const float*)d_in[13];
    const float* a1  = (const float*)d_in[14];
    const float* be1 = (const float*)d_in[15];
    const float* a2  = (const float*)d_in[16];
    const float* be2 = (const float*)d_in[17];
    float* outf = (float*)d_out;   // 4096x1024 fp32 = 16 MB

    // ---- arena (peak 58 MB of ws + d_out reuse) — R13 layout + maskf in d_out[8,8.02) --
    char* ws = (char*)d_ws;
    const size_t MB = 1024 * 1024;
    unsigned short* W2_t   = (unsigned short*)(ws);
    unsigned short* W1_t   = (unsigned short*)(ws + 8 * MB);
    float*          Pbuf   = (float*)(ws + 8 * MB);
    unsigned short* Wqkv_t = (unsigned short*)(ws + 16 * MB);
    float*          bqkv   = (float*)(ws + 22 * MB);
    unsigned short* Kc     = (unsigned short*)(ws + 16 * MB);
    unsigned short* n2     = (unsigned short*)(ws + 16 * MB);
    unsigned short* Wo_t   = (unsigned short*)(ws + 24 * MB);
    unsigned short* Qb     = (unsigned short*)(ws + 26 * MB);
    unsigned short* Kb     = (unsigned short*)(ws + 34 * MB);
    unsigned short* Vb     = (unsigned short*)(ws + 42 * MB);
    unsigned short* ff1    = (unsigned short*)(ws + 26 * MB);
    unsigned short* attnO  = (unsigned short*)(ws + 50 * MB);
    unsigned short* n1     = (unsigned short*)d_out;                 // [0,8) MB, ph1-3
    float*          maskf  = (float*)((char*)d_out + 8 * MB);        // 16 KB, ph1-4
    unsigned short* Vc     = (unsigned short*)d_out;                 // [0,8) MB, ph3.5-4
    float*          hbuf   = (float*)d_out;                          // 16 MB, ph5-9

    // phase 1: weight transposes + bias concat + maskf + LN1, single launch
    prep_weights<<<dim3(16, 16, 22), 256, 0, stream>>>(
        Wq, Wk, Wv, Wo, W1, W2, bq, bk, bv, msk, x, a1, be1,
        Wqkv_t, Wo_t, W1_t, W2_t, bqkv, maskf, n1);

    // phase 3: [Q|K|V] = n1 @ Wqkv + bias, 3 contiguous blocks (SPLIT3, branchless)
    gemm_bt<false, false, unsigned short, true><<<dim3(32, 24), 256, 0, stream>>>(
        n1, Wqkv_t, bqkv, nullptr, Qb, NTOK, 3072, 1024);
    // phase 3.5: pack K (over dead Wqkv_t/bqkv) + V (over dead n1 in d_out)
    pack_kv<<<dim3(32, 16, 2), 256, 0, stream>>>(Kb, Vb, Kc, Vc);
    // phase 4: attention — 64 q/block, 1024 blocks, fixed-max softmax, fma-mask
    attn_kernel<<<dim3(32, 16, 2), 256, 0, stream>>>(Qb, Kc, Vc, maskf, attnO);
    // phase 5: h = x + attnO @ Wo^T + bo  (fp32, into d_out; Vc/maskf dead)
    gemm_bt<false, true, float><<<dim3(32, 8), 256, 0, stream>>>(
        attnO, Wo_t, bo, x, hbuf, NTOK, 1024, 1024);
    // phase 6: n2 = LN2(h)  (bf16, over dead Kc)
    ln_kernel<<<NTOK, 256, 0, stream>>>(hbuf, a2, be2, n2);
    // phase 7: ff1 = relu(n2 @ W1 + b1)  (bf16, over dead Qb/Kb/Vb/attnO)
    gemm_bt<true, false, unsigned short><<<dim3(32, 32), 256, 0, stream>>>(
        n2, W1_t, b1, nullptr, ff1, NTOK, DFF, 1024);
    // phase 8: split-K ff2: z=0 -> out = h + b2 + acc(k<2048); z=1 -> Pbuf = acc(k>=2048)
    ff2_splitk<<<dim3(32, 8, 2), 256, 0, stream>>>(ff1, W2_t, b2, hbuf, outf, Pbuf);
    // phase 9: out += Pbuf
    add_pbuf<<<dim3(2048), 256, 0, stream>>>(outf, Pbuf);
}